// Round 1
// baseline (127.681 us; speedup 1.0000x reference)
//
#include <hip/hip_runtime.h>
#include <math.h>

#define NN 4096
#define DIN 1024
#define DOUT 512
#define ALPHA 0.2f

// ---------------- K1: wa1 = Wf @ a1, wa2 = Wf @ a2  (1024 rows, wave per row)
__global__ void k_wa(const float* __restrict__ Wf, const float* __restrict__ a1,
                     const float* __restrict__ a2, float* __restrict__ wa1,
                     float* __restrict__ wa2) {
    int row  = blockIdx.x * (blockDim.x >> 6) + (threadIdx.x >> 6);
    int lane = threadIdx.x & 63;
    const float* wr = Wf + (size_t)row * DOUT;
    float s1 = 0.f, s2 = 0.f;
    for (int k = lane; k < DOUT; k += 64) {
        float w = wr[k];
        s1 += w * a1[k];
        s2 += w * a2[k];
    }
    for (int off = 32; off; off >>= 1) {
        s1 += __shfl_down(s1, off);
        s2 += __shfl_down(s2, off);
    }
    if (lane == 0) { wa1[row] = s1; wa2[row] = s2; }
}

// ---------------- K2: f1 = x@wa1 + b1, f2 = x@wa2 + b2  (4096 rows, wave per row)
__global__ void k_f(const float* __restrict__ x, const float* __restrict__ wa1,
                    const float* __restrict__ wa2, const float* __restrict__ b1,
                    const float* __restrict__ b2, float* __restrict__ f1,
                    float* __restrict__ f2) {
    int row  = blockIdx.x * (blockDim.x >> 6) + (threadIdx.x >> 6);
    int lane = threadIdx.x & 63;
    const float* xr = x + (size_t)row * DIN;
    float s1 = 0.f, s2 = 0.f;
    for (int k = lane; k < DIN; k += 64) {
        float xv = xr[k];
        s1 += xv * wa1[k];
        s2 += xv * wa2[k];
    }
    for (int off = 32; off; off >>= 1) {
        s1 += __shfl_down(s1, off);
        s2 += __shfl_down(s2, off);
    }
    if (lane == 0) { f1[row] = s1 + b1[0]; f2[row] = s2 + b2[0]; }
}

// ---------------- K3: per-row masked softmax stats: m_i, 1/Z_i (block per row)
__global__ __launch_bounds__(256) void k_stats(const float* __restrict__ adj,
                                               const float* __restrict__ f1,
                                               const float* __restrict__ f2,
                                               float* __restrict__ m_out,
                                               float* __restrict__ rZ_out) {
    int row = blockIdx.x, tid = threadIdx.x;
    const float* ar = adj + (size_t)row * NN;
    float f1r = f1[row];
    float e[16];
    float lmax = -INFINITY;
#pragma unroll
    for (int t = 0; t < 16; t++) {
        int j  = tid + 256 * t;
        float a = ar[j];
        float v = -INFINITY;
        if (a != 0.0f) {
            float l = f1r + f2[j];
            v = (l >= 0.f) ? l : ALPHA * l;
        }
        e[t] = v;
        lmax = fmaxf(lmax, v);
    }
    __shared__ float wmax[4], wsum[4];
    for (int off = 32; off; off >>= 1) lmax = fmaxf(lmax, __shfl_down(lmax, off));
    if ((tid & 63) == 0) wmax[tid >> 6] = lmax;
    __syncthreads();
    float bmax = fmaxf(fmaxf(wmax[0], wmax[1]), fmaxf(wmax[2], wmax[3]));
    float lsum = 0.f;
#pragma unroll
    for (int t = 0; t < 16; t++) {
        if (e[t] != -INFINITY) lsum += __expf(e[t] - bmax);
    }
    for (int off = 32; off; off >>= 1) lsum += __shfl_down(lsum, off);
    if ((tid & 63) == 0) wsum[tid >> 6] = lsum;
    __syncthreads();
    if (tid == 0) {
        float Z = wsum[0] + wsum[1] + wsum[2] + wsum[3];
        m_out[row]  = bmax;
        rZ_out[row] = 1.0f / Z;
    }
}

// ---------------- K4: colsum_j via symmetric row pass; s_j (block per row)
__global__ __launch_bounds__(256) void k_s(const float* __restrict__ adj,
                                           const float* __restrict__ f1,
                                           const float* __restrict__ f2,
                                           const float* __restrict__ m,
                                           const float* __restrict__ rZ,
                                           float* __restrict__ s_out) {
    int row = blockIdx.x, tid = threadIdx.x;
    const float* ar = adj + (size_t)row * NN;
    float f2r = f2[row];
    float lsum = 0.f;
#pragma unroll
    for (int t = 0; t < 16; t++) {
        int i  = tid + 256 * t;
        float a = ar[i];
        if (a != 0.0f) {
            float l = f1[i] + f2r;
            float e = (l >= 0.f) ? l : ALPHA * l;
            lsum += __expf(e - m[i]) * rZ[i];
        }
    }
    __shared__ float wsum[4];
    for (int off = 32; off; off >>= 1) lsum += __shfl_down(lsum, off);
    if ((tid & 63) == 0) wsum[tid >> 6] = lsum;
    __syncthreads();
    if (tid == 0) {
        float colsum = wsum[0] + wsum[1] + wsum[2] + wsum[3];
        float l  = f1[row] + f2r;
        float e  = (l >= 0.f) ? l : ALPHA * l;
        float cjj = __expf(e - m[row]) * rZ[row];
        // rowsum_i = 1 (identity) + 0.5*(row softmax sum = 1) + 0.5*colsum
        s_out[row] = (cjj + 1.0f) / (1.5f + 0.5f * colsum);
    }
}

// ---------------- K5: out = relu(diag(s) @ (x @ W)); 64x64 tile, 4x4/thread
__global__ __launch_bounds__(256) void k_gemm(const float* __restrict__ x,
                                              const float* __restrict__ W,
                                              const float* __restrict__ s,
                                              float* __restrict__ out) {
    const int BM = 64, BN = 64, BK = 16;
    __shared__ float As[BK][BM];   // transposed: [k][m]
    __shared__ float Bs[BK][BN];   // natural:    [k][n]
    int bn  = blockIdx.x * BN;
    int bm  = blockIdx.y * BM;
    int tid = threadIdx.x;
    int tr = tid >> 4;            // 0..15 -> m block of 4
    int tc = tid & 15;            // 0..15 -> n block of 4

    // A tile load: 64 rows x 16 cols, thread -> 1 float4
    int arow = tid >> 2;          // 0..63
    int acol = (tid & 3) << 2;    // 0,4,8,12
    // B tile load: 16 rows x 64 cols, thread -> 1 float4
    int brow = tid >> 4;          // 0..15
    int bcol = (tid & 15) << 2;   // 0..60

    const float* xg = x + (size_t)(bm + arow) * DIN + acol;
    const float* wg = W + (size_t)brow * DOUT + bn + bcol;

    float acc[4][4] = {};

    for (int k0 = 0; k0 < DIN; k0 += BK) {
        float4 av = *(const float4*)(xg + k0);
        float4 bv = *(const float4*)(wg + (size_t)k0 * DOUT);
        As[acol + 0][arow] = av.x;
        As[acol + 1][arow] = av.y;
        As[acol + 2][arow] = av.z;
        As[acol + 3][arow] = av.w;
        *(float4*)&Bs[brow][bcol] = bv;
        __syncthreads();
#pragma unroll
        for (int kk = 0; kk < BK; kk++) {
            float a[4], b[4];
            *(float4*)a = *(const float4*)&As[kk][tr << 2];
            *(float4*)b = *(const float4*)&Bs[kk][tc << 2];
#pragma unroll
            for (int i = 0; i < 4; i++)
#pragma unroll
                for (int j = 0; j < 4; j++) acc[i][j] += a[i] * b[j];
        }
        __syncthreads();
    }

#pragma unroll
    for (int i = 0; i < 4; i++) {
        int r = bm + (tr << 2) + i;
        float sv = s[r];
        float4 o;
        o.x = fmaxf(acc[i][0] * sv, 0.f);
        o.y = fmaxf(acc[i][1] * sv, 0.f);
        o.z = fmaxf(acc[i][2] * sv, 0.f);
        o.w = fmaxf(acc[i][3] * sv, 0.f);
        *(float4*)(out + (size_t)r * DOUT + bn + (tc << 2)) = o;
    }
}

extern "C" void kernel_launch(void* const* d_in, const int* in_sizes, int n_in,
                              void* d_out, int out_size, void* d_ws, size_t ws_size,
                              hipStream_t stream) {
    const float* x   = (const float*)d_in[0];
    const float* adj = (const float*)d_in[1];
    const float* Wf  = (const float*)d_in[2];
    const float* a1  = (const float*)d_in[3];
    const float* b1  = (const float*)d_in[4];
    const float* a2  = (const float*)d_in[5];
    const float* b2  = (const float*)d_in[6];
    const float* W   = (const float*)d_in[7];
    float* out = (float*)d_out;

    float* ws  = (float*)d_ws;
    float* wa1 = ws;               // 1024
    float* wa2 = wa1 + DIN;        // 1024
    float* f1  = wa2 + DIN;        // 4096
    float* f2  = f1 + NN;          // 4096
    float* m   = f2 + NN;          // 4096
    float* rZ  = m + NN;           // 4096
    float* s   = rZ + NN;          // 4096

    // K1: 1024 rows, 4 waves/block -> 256 blocks
    k_wa<<<256, 256, 0, stream>>>(Wf, a1, a2, wa1, wa2);
    // K2: 4096 rows, 4 waves/block -> 1024 blocks
    k_f<<<1024, 256, 0, stream>>>(x, wa1, wa2, b1, b2, f1, f2);
    // K3: block per row
    k_stats<<<NN, 256, 0, stream>>>(adj, f1, f2, m, rZ);
    // K4: block per row
    k_s<<<NN, 256, 0, stream>>>(adj, f1, f2, m, rZ, s);
    // K5: GEMM + diag scale + relu
    dim3 gg(DOUT / 64, NN / 64);
    k_gemm<<<gg, 256, 0, stream>>>(x, W, s, out);
}

// Round 2
// 66.741 us; speedup vs baseline: 1.9131x; 1.9131x over previous
//
#include <hip/hip_runtime.h>
#include <stdint.h>
#include <math.h>

#define NN 4096
#define DIN 1024
#define DOUT 512
#define ALPHA 0.2f

typedef __attribute__((ext_vector_type(8))) short short8;
typedef __attribute__((ext_vector_type(4))) float f32x4;

__device__ __forceinline__ unsigned short f2bf(float f) {
    uint32_t u = __float_as_uint(f);
    u += 0x7fffu + ((u >> 16) & 1u);
    return (unsigned short)(u >> 16);
}

__device__ __forceinline__ void async16(const void* g, void* l) {
    __builtin_amdgcn_global_load_lds(
        (const __attribute__((address_space(1))) uint32_t*)g,
        (__attribute__((address_space(3))) uint32_t*)l, 16, 0, 0);
}

// ---------------- K1: wa1 = Wf @ a1, wa2 = Wf @ a2  (wave per row)
__global__ void k_wa(const float* __restrict__ Wf, const float* __restrict__ a1,
                     const float* __restrict__ a2, float* __restrict__ wa1,
                     float* __restrict__ wa2) {
    int row  = blockIdx.x * (blockDim.x >> 6) + (threadIdx.x >> 6);
    int lane = threadIdx.x & 63;
    const float* wr = Wf + (size_t)row * DOUT;
    float s1 = 0.f, s2 = 0.f;
    for (int k = lane; k < DOUT; k += 64) {
        float w = wr[k];
        s1 += w * a1[k];
        s2 += w * a2[k];
    }
    for (int off = 32; off; off >>= 1) {
        s1 += __shfl_down(s1, off);
        s2 += __shfl_down(s2, off);
    }
    if (lane == 0) { wa1[row] = s1; wa2[row] = s2; }
}

// ---------------- K2: f1,f2 GEMV + x -> bf16 (pre-swizzled granules), x read ONCE
__global__ __launch_bounds__(128) void k_fx(const float* __restrict__ x,
    const float* __restrict__ wa1, const float* __restrict__ wa2,
    const float* __restrict__ b1, const float* __restrict__ b2,
    float* __restrict__ f1, float* __restrict__ f2,
    unsigned short* __restrict__ xb) {
    int row = blockIdx.x, tid = threadIdx.x;      // tid = k-granule 0..127
    const float* xr = x + (size_t)row * DIN + tid * 8;
    float4 v0 = *(const float4*)xr;
    float4 v1 = *(const float4*)(xr + 4);
    float xv[8] = {v0.x, v0.y, v0.z, v0.w, v1.x, v1.y, v1.z, v1.w};
    int k = tid * 8;
    float s1 = 0.f, s2 = 0.f;
#pragma unroll
    for (int j = 0; j < 8; ++j) {
        s1 += xv[j] * wa1[k + j];
        s2 += xv[j] * wa2[k + j];
    }
    union { unsigned short u[8]; uint4 q; } pk;
#pragma unroll
    for (int j = 0; j < 8; ++j) pk.u[j] = f2bf(xv[j]);
    int sw = (row >> 1) & 3;
    int p  = (tid & ~3) | ((tid & 3) ^ sw);       // bake XOR swizzle into storage
    *(uint4*)(xb + (size_t)row * DIN + p * 8) = pk.q;
    for (int off = 32; off; off >>= 1) {
        s1 += __shfl_down(s1, off);
        s2 += __shfl_down(s2, off);
    }
    __shared__ float red[4];
    int lane = tid & 63, wid = tid >> 6;
    if (lane == 0) { red[wid] = s1; red[2 + wid] = s2; }
    __syncthreads();
    if (tid == 0) f1[row] = red[0] + red[1] + b1[0];
    if (tid == 1) f2[row] = red[2] + red[3] + b2[0];
}

// ---------------- K3: W -> Wt bf16 transposed [N][K], pre-swizzled granules
__global__ __launch_bounds__(256) void k_wt(const float* __restrict__ W,
                                            unsigned short* __restrict__ wt) {
    int tid = threadIdx.x;
    int n = blockIdx.x * 64 + (tid & 63);
    int g = blockIdx.y * 4 + (tid >> 6);          // k-granule 0..127
    float v[8];
#pragma unroll
    for (int j = 0; j < 8; ++j) v[j] = W[(size_t)(g * 8 + j) * DOUT + n];
    union { unsigned short u[8]; uint4 q; } pk;
#pragma unroll
    for (int j = 0; j < 8; ++j) pk.u[j] = f2bf(v[j]);
    int sw = (n >> 1) & 3;
    int p  = (g & ~3) | ((g & 3) ^ sw);
    *(uint4*)(wt + (size_t)n * DIN + p * 8) = pk.q;
}

// ---------------- K4: per-row softmax stats m_i, 1/Z_i + adjacency bitmask
__global__ __launch_bounds__(256) void k_stats(const float* __restrict__ adj,
                                               const float* __restrict__ f1,
                                               const float* __restrict__ f2,
                                               float* __restrict__ m_out,
                                               float* __restrict__ rZ_out,
                                               unsigned long long* __restrict__ bits) {
    int row = blockIdx.x, tid = threadIdx.x;
    int lane = tid & 63, wid = tid >> 6;
    const float* ar = adj + (size_t)row * NN;
    float f1r = f1[row];
    float e[16];
    float lmax = -INFINITY;
#pragma unroll
    for (int t = 0; t < 16; t++) {
        int j  = tid + 256 * t;
        float a = ar[j];
        unsigned long long msk = __ballot(a != 0.0f);
        if (lane == 0) bits[(size_t)row * 64 + wid + 4 * t] = msk;
        float v = -INFINITY;
        if (a != 0.0f) {
            float l = f1r + f2[j];
            v = (l >= 0.f) ? l : ALPHA * l;
        }
        e[t] = v;
        lmax = fmaxf(lmax, v);
    }
    __shared__ float wmax[4], wsum[4];
    for (int off = 32; off; off >>= 1) lmax = fmaxf(lmax, __shfl_down(lmax, off));
    if (lane == 0) wmax[wid] = lmax;
    __syncthreads();
    float bmax = fmaxf(fmaxf(wmax[0], wmax[1]), fmaxf(wmax[2], wmax[3]));
    float lsum = 0.f;
#pragma unroll
    for (int t = 0; t < 16; t++) {
        if (e[t] != -INFINITY) lsum += __expf(e[t] - bmax);
    }
    for (int off = 32; off; off >>= 1) lsum += __shfl_down(lsum, off);
    if (lane == 0) wsum[wid] = lsum;
    __syncthreads();
    if (tid == 0) {
        float Z = wsum[0] + wsum[1] + wsum[2] + wsum[3];
        m_out[row]  = bmax;
        rZ_out[row] = 1.0f / Z;
    }
}

// ---------------- K5: colsum via bitmask walk (1 wave per row) -> s_j
__global__ __launch_bounds__(64) void k_s(const unsigned long long* __restrict__ bits,
                                          const float* __restrict__ f1,
                                          const float* __restrict__ f2,
                                          const float* __restrict__ m,
                                          const float* __restrict__ rZ,
                                          float* __restrict__ s_out) {
    int row = blockIdx.x, lane = threadIdx.x;
    unsigned long long w = bits[(size_t)row * 64 + lane];
    float f2r = f2[row];
    float sum = 0.f;
    while (w) {
        int b = __builtin_ctzll(w);
        w &= w - 1;
        int i = lane * 64 + b;
        float l = f1[i] + f2r;
        float e = (l >= 0.f) ? l : ALPHA * l;
        sum += __expf(e - m[i]) * rZ[i];
    }
    for (int off = 32; off; off >>= 1) sum += __shfl_down(sum, off);
    if (lane == 0) {
        float l   = f1[row] + f2r;
        float e   = (l >= 0.f) ? l : ALPHA * l;
        float cjj = __expf(e - m[row]) * rZ[row];
        s_out[row] = (cjj + 1.0f) / (1.5f + 0.5f * sum);
    }
}

// ---------------- K6: out = relu(diag(s) @ (xb @ Wt^T)), bf16 MFMA
// 128x64 tile, BK=32, 4 waves each 64x32, double-buffered global_load_lds.
__global__ __launch_bounds__(256) void k_gemm(const unsigned short* __restrict__ xb,
                                              const unsigned short* __restrict__ wt,
                                              const float* __restrict__ s,
                                              float* __restrict__ out) {
    __shared__ __align__(16) unsigned short As[2][128][32];
    __shared__ __align__(16) unsigned short Bs[2][64][32];
    // XCD-chunked block remap: each XCD gets 4 consecutive M-strips x all N.
    int lid = blockIdx.y * gridDim.x + blockIdx.x;   // 0..255
    int xcd = lid & 7, idx = lid >> 3;
    int by = xcd * 4 + (idx & 3);                    // 0..31
    int bx = idx >> 2;                               // 0..7
    int bm = by * 128, bn = bx * 64;

    int tid = threadIdx.x, wid = tid >> 6, lane = tid & 63;
    int wr = wid >> 1, wc = wid & 1;

    // staging: per-lane global source (linear; swizzle is baked into xb/wt)
    int srow = lane >> 2, sg = lane & 3;
    const unsigned short* ga0 = xb + (size_t)(bm + wid * 32 + srow) * DIN + sg * 8;
    const unsigned short* gb0 = wt + (size_t)(bn + wid * 16 + srow) * DIN + sg * 8;

    int r15 = lane & 15, gl = lane >> 4;
    int gofs = (gl ^ ((r15 >> 1) & 3)) * 8;          // XOR-swizzled read offset

    f32x4 acc[4][2] = {};

#define STAGE(BUF, K0) do {                                              \
        async16(ga0 + (K0),            &As[BUF][wid * 32][0]);           \
        async16(ga0 + (K0) + 16 * DIN, &As[BUF][wid * 32 + 16][0]);      \
        async16(gb0 + (K0),            &Bs[BUF][wid * 16][0]);           \
    } while (0)

#define COMPUTE(BUF) do {                                                \
        const unsigned short* pa = &As[BUF][wr * 64 + r15][gofs];        \
        const unsigned short* pb = &Bs[BUF][wc * 32 + r15][gofs];        \
        short8 af0 = *(const short8*)(pa);                               \
        short8 af1 = *(const short8*)(pa + 16 * 32);                     \
        short8 af2 = *(const short8*)(pa + 32 * 32);                     \
        short8 af3 = *(const short8*)(pa + 48 * 32);                     \
        short8 bf0 = *(const short8*)(pb);                               \
        short8 bf1 = *(const short8*)(pb + 16 * 32);                     \
        acc[0][0] = __builtin_amdgcn_mfma_f32_16x16x32_bf16(af0, bf0, acc[0][0], 0, 0, 0); \
        acc[0][1] = __builtin_amdgcn_mfma_f32_16x16x32_bf16(af0, bf1, acc[0][1], 0, 0, 0); \
        acc[1][0] = __builtin_amdgcn_mfma_f32_16x16x32_bf16(af1, bf0, acc[1][0], 0, 0, 0); \
        acc[1][1] = __builtin_amdgcn_mfma_f32_16x16x32_bf16(af1, bf1, acc[1][1], 0, 0, 0); \
        acc[2][0] = __builtin_amdgcn_mfma_f32_16x16x32_bf16(af2, bf0, acc[2][0], 0, 0, 0); \
        acc[2][1] = __builtin_amdgcn_mfma_f32_16x16x32_bf16(af2, bf1, acc[2][1], 0, 0, 0); \
        acc[3][0] = __builtin_amdgcn_mfma_f32_16x16x32_bf16(af3, bf0, acc[3][0], 0, 0, 0); \
        acc[3][1] = __builtin_amdgcn_mfma_f32_16x16x32_bf16(af3, bf1, acc[3][1], 0, 0, 0); \
    } while (0)

    STAGE(0, 0);
    asm volatile("s_waitcnt vmcnt(0)" ::: "memory");
    __syncthreads();
    int cur = 0;
    for (int t = 0; t < (DIN / 32) - 1; ++t) {
        STAGE(cur ^ 1, (t + 1) * 32);
        COMPUTE(cur);
        asm volatile("s_waitcnt vmcnt(0)" ::: "memory");
        __syncthreads();
        cur ^= 1;
    }
    COMPUTE(cur);

#pragma unroll
    for (int mi = 0; mi < 4; ++mi) {
        int crow0 = bm + wr * 64 + mi * 16 + gl * 4;
#pragma unroll
        for (int ni = 0; ni < 2; ++ni) {
            int ccol = bn + wc * 32 + ni * 16 + r15;
#pragma unroll
            for (int r = 0; r < 4; ++r) {
                int row = crow0 + r;
                float v = acc[mi][ni][r] * s[row];
                out[(size_t)row * DOUT + ccol] = fmaxf(v, 0.f);
            }
        }
    }
#undef STAGE
#undef COMPUTE
}

extern "C" void kernel_launch(void* const* d_in, const int* in_sizes, int n_in,
                              void* d_out, int out_size, void* d_ws, size_t ws_size,
                              hipStream_t stream) {
    const float* x   = (const float*)d_in[0];
    const float* adj = (const float*)d_in[1];
    const float* Wf  = (const float*)d_in[2];
    const float* a1  = (const float*)d_in[3];
    const float* b1  = (const float*)d_in[4];
    const float* a2  = (const float*)d_in[5];
    const float* b2  = (const float*)d_in[6];
    const float* W   = (const float*)d_in[7];
    float* out = (float*)d_out;

    char* w = (char*)d_ws;
    float* wa1 = (float*)(w + 0);
    float* wa2 = (float*)(w + 4096);
    float* f1  = (float*)(w + 16384);
    float* f2  = (float*)(w + 32768);
    float* m   = (float*)(w + 49152);
    float* rZ  = (float*)(w + 65536);
    float* s   = (float*)(w + 81920);
    unsigned long long* bits = (unsigned long long*)(w + 98304);     // 2 MB
    unsigned short* xb = (unsigned short*)(w + 2195456);             // 8 MB
    unsigned short* wt = (unsigned short*)(w + 10584064);            // 1 MB

    k_wt<<<dim3(8, 32), 256, 0, stream>>>(W, wt);
    k_wa<<<256, 256, 0, stream>>>(Wf, a1, a2, wa1, wa2);
    k_fx<<<NN, 128, 0, stream>>>(x, wa1, wa2, b1, b2, f1, f2, xb);
    k_stats<<<NN, 256, 0, stream>>>(adj, f1, f2, m, rZ, bits);
    k_s<<<NN, 64, 0, stream>>>(bits, f1, f2, m, rZ, s);
    dim3 gg(8, 32);
    k_gemm<<<gg, 256, 0, stream>>>(xb, wt, s, out);
}

// Round 3
// 60.626 us; speedup vs baseline: 2.1061x; 1.1009x over previous
//
#include <hip/hip_runtime.h>
#include <stdint.h>
#include <math.h>

#define NN 4096
#define DIN 1024
#define DOUT 512
#define ALPHA 0.2f

typedef __attribute__((ext_vector_type(8))) short short8;
typedef __attribute__((ext_vector_type(4))) float f32x4;

__device__ __forceinline__ unsigned short f2bf(float f) {
    uint32_t u = __float_as_uint(f);
    u += 0x7fffu + ((u >> 16) & 1u);
    return (unsigned short)(u >> 16);
}

__device__ __forceinline__ void async16(const void* g, void* l) {
    __builtin_amdgcn_global_load_lds(
        (const __attribute__((address_space(1))) uint32_t*)g,
        (__attribute__((address_space(3))) uint32_t*)l, 16, 0, 0);
}

// ---------------- K1: wa1 = Wf @ a1, wa2 = Wf @ a2  (wave per row)
__global__ void k_wa(const float* __restrict__ Wf, const float* __restrict__ a1,
                     const float* __restrict__ a2, float* __restrict__ wa1,
                     float* __restrict__ wa2) {
    int row  = blockIdx.x * (blockDim.x >> 6) + (threadIdx.x >> 6);
    int lane = threadIdx.x & 63;
    const float* wr = Wf + (size_t)row * DOUT;
    float s1 = 0.f, s2 = 0.f;
    for (int k = lane; k < DOUT; k += 64) {
        float w = wr[k];
        s1 += w * a1[k];
        s2 += w * a2[k];
    }
    for (int off = 32; off; off >>= 1) {
        s1 += __shfl_down(s1, off);
        s2 += __shfl_down(s2, off);
    }
    if (lane == 0) { wa1[row] = s1; wa2[row] = s2; }
}

// ---------------- K2: f1,f2 GEMV + x -> bf16 (pre-swizzled granules), x read ONCE
__global__ __launch_bounds__(128) void k_fx(const float* __restrict__ x,
    const float* __restrict__ wa1, const float* __restrict__ wa2,
    const float* __restrict__ b1, const float* __restrict__ b2,
    float* __restrict__ f1, float* __restrict__ f2,
    unsigned short* __restrict__ xb) {
    int row = blockIdx.x, tid = threadIdx.x;      // tid = k-granule 0..127
    const float* xr = x + (size_t)row * DIN + tid * 8;
    float4 v0 = *(const float4*)xr;
    float4 v1 = *(const float4*)(xr + 4);
    float xv[8] = {v0.x, v0.y, v0.z, v0.w, v1.x, v1.y, v1.z, v1.w};
    int k = tid * 8;
    float s1 = 0.f, s2 = 0.f;
#pragma unroll
    for (int j = 0; j < 8; ++j) {
        s1 += xv[j] * wa1[k + j];
        s2 += xv[j] * wa2[k + j];
    }
    union { unsigned short u[8]; uint4 q; } pk;
#pragma unroll
    for (int j = 0; j < 8; ++j) pk.u[j] = f2bf(xv[j]);
    int sw = (row >> 1) & 3;
    int p  = (tid & ~3) | ((tid & 3) ^ sw);       // bake XOR swizzle into storage
    *(uint4*)(xb + (size_t)row * DIN + p * 8) = pk.q;
    for (int off = 32; off; off >>= 1) {
        s1 += __shfl_down(s1, off);
        s2 += __shfl_down(s2, off);
    }
    __shared__ float red[4];
    int lane = tid & 63, wid = tid >> 6;
    if (lane == 0) { red[wid] = s1; red[2 + wid] = s2; }
    __syncthreads();
    if (tid == 0) f1[row] = red[0] + red[1] + b1[0];
    if (tid == 1) f2[row] = red[2] + red[3] + b2[0];
}

// ---------------- K3: W -> Wt bf16 transposed [N][K], pre-swizzled granules
__global__ __launch_bounds__(256) void k_wt(const float* __restrict__ W,
                                            unsigned short* __restrict__ wt) {
    int tid = threadIdx.x;
    int n = blockIdx.x * 64 + (tid & 63);
    int g = blockIdx.y * 4 + (tid >> 6);          // k-granule 0..127
    float v[8];
#pragma unroll
    for (int j = 0; j < 8; ++j) v[j] = W[(size_t)(g * 8 + j) * DOUT + n];
    union { unsigned short u[8]; uint4 q; } pk;
#pragma unroll
    for (int j = 0; j < 8; ++j) pk.u[j] = f2bf(v[j]);
    int sw = (n >> 1) & 3;
    int p  = (g & ~3) | ((g & 3) ^ sw);
    *(uint4*)(wt + (size_t)n * DIN + p * 8) = pk.q;
}

// ---------------- K4: per-row softmax stats m_i, 1/Z_i + adjacency bitmask
// One pass: thread tid owns 16 CONSECUTIVE columns [16*tid, 16*tid+16),
// loaded as 4x float4 (1 KB/wave per instruction).
__global__ __launch_bounds__(256) void k_stats(const float* __restrict__ adj,
                                               const float* __restrict__ f1,
                                               const float* __restrict__ f2,
                                               float* __restrict__ m_out,
                                               float* __restrict__ rZ_out,
                                               unsigned long long* __restrict__ bits) {
    int row = blockIdx.x, tid = threadIdx.x;
    int lane = tid & 63, wid = tid >> 6;
    const float4* ar4 = (const float4*)(adj + (size_t)row * NN);
    float f1r = f1[row];
    float v[16];
#pragma unroll
    for (int i = 0; i < 4; ++i) {
        float4 a = ar4[tid * 4 + i];
        v[4 * i + 0] = a.x; v[4 * i + 1] = a.y;
        v[4 * i + 2] = a.z; v[4 * i + 3] = a.w;
    }
    int c0 = tid * 16;
    unsigned int m16 = 0;
    float e[16];
    float lmax = -INFINITY;
#pragma unroll
    for (int k = 0; k < 16; ++k) {
        bool nz = (v[k] != 0.0f);
        float val = -INFINITY;
        if (nz) {
            m16 |= (1u << k);
            float l = f1r + f2[c0 + k];
            val = (l >= 0.f) ? l : ALPHA * l;
        }
        e[k] = val;
        lmax = fmaxf(lmax, val);
    }
    // assemble 64-bit mask words from 4 consecutive lanes (word = tid/4)
    unsigned long long um = (unsigned long long)m16 << ((lane & 3) * 16);
    um |= __shfl_xor(um, 1);
    um |= __shfl_xor(um, 2);
    if ((lane & 3) == 0) bits[(size_t)row * 64 + (tid >> 2)] = um;

    __shared__ float wmax[4], wsum[4];
    for (int off = 32; off; off >>= 1) lmax = fmaxf(lmax, __shfl_down(lmax, off));
    if (lane == 0) wmax[wid] = lmax;
    __syncthreads();
    float bmax = fmaxf(fmaxf(wmax[0], wmax[1]), fmaxf(wmax[2], wmax[3]));
    float lsum = 0.f;
#pragma unroll
    for (int k = 0; k < 16; ++k) {
        if (e[k] != -INFINITY) lsum += __expf(e[k] - bmax);
    }
    for (int off = 32; off; off >>= 1) lsum += __shfl_down(lsum, off);
    if (lane == 0) wsum[wid] = lsum;
    __syncthreads();
    if (tid == 0) {
        float Z = wsum[0] + wsum[1] + wsum[2] + wsum[3];
        m_out[row]  = bmax;
        rZ_out[row] = 1.0f / Z;
    }
}

// ---------------- K5: colsum via bitmask walk (1 wave per row) -> s_j
__global__ __launch_bounds__(64) void k_s(const unsigned long long* __restrict__ bits,
                                          const float* __restrict__ f1,
                                          const float* __restrict__ f2,
                                          const float* __restrict__ m,
                                          const float* __restrict__ rZ,
                                          float* __restrict__ s_out) {
    int row = blockIdx.x, lane = threadIdx.x;
    unsigned long long w = bits[(size_t)row * 64 + lane];
    float f2r = f2[row];
    float sum = 0.f;
    while (w) {
        int b = __builtin_ctzll(w);
        w &= w - 1;
        int i = lane * 64 + b;
        float l = f1[i] + f2r;
        float e = (l >= 0.f) ? l : ALPHA * l;
        sum += __expf(e - m[i]) * rZ[i];
    }
    for (int off = 32; off; off >>= 1) sum += __shfl_down(sum, off);
    if (lane == 0) {
        float l   = f1[row] + f2r;
        float e   = (l >= 0.f) ? l : ALPHA * l;
        float cjj = __expf(e - m[row]) * rZ[row];
        s_out[row] = (cjj + 1.0f) / (1.5f + 0.5f * sum);
    }
}

// ---------------- K6: out = relu(diag(s) @ (xb @ Wt^T)), bf16 MFMA
// 128x64 tile, BK=32, 4 waves each 64x32, double-buffered global_load_lds.
__global__ __launch_bounds__(256) void k_gemm(const unsigned short* __restrict__ xb,
                                              const unsigned short* __restrict__ wt,
                                              const float* __restrict__ s,
                                              float* __restrict__ out) {
    __shared__ __align__(16) unsigned short As[2][128][32];
    __shared__ __align__(16) unsigned short Bs[2][64][32];
    // XCD-chunked block remap: each XCD gets 4 consecutive M-strips x all N.
    int lid = blockIdx.y * gridDim.x + blockIdx.x;   // 0..255
    int xcd = lid & 7, idx = lid >> 3;
    int by = xcd * 4 + (idx & 3);                    // 0..31
    int bx = idx >> 2;                               // 0..7
    int bm = by * 128, bn = bx * 64;

    int tid = threadIdx.x, wid = tid >> 6, lane = tid & 63;
    int wr = wid >> 1, wc = wid & 1;

    // staging: per-lane global source (linear; swizzle is baked into xb/wt)
    int srow = lane >> 2, sg = lane & 3;
    const unsigned short* ga0 = xb + (size_t)(bm + wid * 32 + srow) * DIN + sg * 8;
    const unsigned short* gb0 = wt + (size_t)(bn + wid * 16 + srow) * DIN + sg * 8;

    int r15 = lane & 15, gl = lane >> 4;
    int gofs = (gl ^ ((r15 >> 1) & 3)) * 8;          // XOR-swizzled read offset

    f32x4 acc[4][2] = {};

#define STAGE(BUF, K0) do {                                              \
        async16(ga0 + (K0),            &As[BUF][wid * 32][0]);           \
        async16(ga0 + (K0) + 16 * DIN, &As[BUF][wid * 32 + 16][0]);      \
        async16(gb0 + (K0),            &Bs[BUF][wid * 16][0]);           \
    } while (0)

#define COMPUTE(BUF) do {                                                \
        const unsigned short* pa = &As[BUF][wr * 64 + r15][gofs];        \
        const unsigned short* pb = &Bs[BUF][wc * 32 + r15][gofs];        \
        short8 af0 = *(const short8*)(pa);                               \
        short8 af1 = *(const short8*)(pa + 16 * 32);                     \
        short8 af2 = *(const short8*)(pa + 32 * 32);                     \
        short8 af3 = *(const short8*)(pa + 48 * 32);                     \
        short8 bf0 = *(const short8*)(pb);                               \
        short8 bf1 = *(const short8*)(pb + 16 * 32);                     \
        acc[0][0] = __builtin_amdgcn_mfma_f32_16x16x32_bf16(af0, bf0, acc[0][0], 0, 0, 0); \
        acc[0][1] = __builtin_amdgcn_mfma_f32_16x16x32_bf16(af0, bf1, acc[0][1], 0, 0, 0); \
        acc[1][0] = __builtin_amdgcn_mfma_f32_16x16x32_bf16(af1, bf0, acc[1][0], 0, 0, 0); \
        acc[1][1] = __builtin_amdgcn_mfma_f32_16x16x32_bf16(af1, bf1, acc[1][1], 0, 0, 0); \
        acc[2][0] = __builtin_amdgcn_mfma_f32_16x16x32_bf16(af2, bf0, acc[2][0], 0, 0, 0); \
        acc[2][1] = __builtin_amdgcn_mfma_f32_16x16x32_bf16(af2, bf1, acc[2][1], 0, 0, 0); \
        acc[3][0] = __builtin_amdgcn_mfma_f32_16x16x32_bf16(af3, bf0, acc[3][0], 0, 0, 0); \
        acc[3][1] = __builtin_amdgcn_mfma_f32_16x16x32_bf16(af3, bf1, acc[3][1], 0, 0, 0); \
    } while (0)

    STAGE(0, 0);
    asm volatile("s_waitcnt vmcnt(0)" ::: "memory");
    __syncthreads();
    int cur = 0;
    for (int t = 0; t < (DIN / 32) - 1; ++t) {
        STAGE(cur ^ 1, (t + 1) * 32);
        COMPUTE(cur);
        asm volatile("s_waitcnt vmcnt(0)" ::: "memory");
        __syncthreads();
        cur ^= 1;
    }
    COMPUTE(cur);

#pragma unroll
    for (int mi = 0; mi < 4; ++mi) {
        int crow0 = bm + wr * 64 + mi * 16 + gl * 4;
#pragma unroll
        for (int ni = 0; ni < 2; ++ni) {
            int ccol = bn + wc * 32 + ni * 16 + r15;
#pragma unroll
            for (int r = 0; r < 4; ++r) {
                int row = crow0 + r;
                float v = acc[mi][ni][r] * s[row];
                out[(size_t)row * DOUT + ccol] = fmaxf(v, 0.f);
            }
        }
    }
#undef STAGE
#undef COMPUTE
}

extern "C" void kernel_launch(void* const* d_in, const int* in_sizes, int n_in,
                              void* d_out, int out_size, void* d_ws, size_t ws_size,
                              hipStream_t stream) {
    const float* x   = (const float*)d_in[0];
    const float* adj = (const float*)d_in[1];
    const float* Wf  = (const float*)d_in[2];
    const float* a1  = (const float*)d_in[3];
    const float* b1  = (const float*)d_in[4];
    const float* a2  = (const float*)d_in[5];
    const float* b2  = (const float*)d_in[6];
    const float* W   = (const float*)d_in[7];
    float* out = (float*)d_out;

    char* w = (char*)d_ws;
    float* wa1 = (float*)(w + 0);
    float* wa2 = (float*)(w + 4096);
    float* f1  = (float*)(w + 16384);
    float* f2  = (float*)(w + 32768);
    float* m   = (float*)(w + 49152);
    float* rZ  = (float*)(w + 65536);
    float* s   = (float*)(w + 81920);
    unsigned long long* bits = (unsigned long long*)(w + 98304);     // 2 MB
    unsigned short* xb = (unsigned short*)(w + 2195456);             // 8 MB
    unsigned short* wt = (unsigned short*)(w + 10584064);            // 1 MB

    k_wt<<<dim3(8, 32), 256, 0, stream>>>(W, wt);
    k_wa<<<256, 256, 0, stream>>>(Wf, a1, a2, wa1, wa2);
    k_fx<<<NN, 128, 0, stream>>>(x, wa1, wa2, b1, b2, f1, f2, xb);
    k_stats<<<NN, 256, 0, stream>>>(adj, f1, f2, m, rZ, bits);
    k_s<<<NN, 64, 0, stream>>>(bits, f1, f2, m, rZ, s);
    dim3 gg(8, 32);
    k_gemm<<<gg, 256, 0, stream>>>(xb, wt, s, out);
}